// Round 1
// baseline (282.972 us; speedup 1.0000x reference)
//
#include <hip/hip_runtime.h>

#define D_FEAT 256

// One wave (64 lanes) per edge: row of 256 f32 = 64 lanes x float4.
// Grid-stride over edges at full occupancy.
__global__ __launch_bounds__(256) void edge_dot_kernel(
    const float* __restrict__ h,
    const int*   __restrict__ src,
    const int*   __restrict__ dst,
    float*       __restrict__ out,
    int n_edges)
{
    const int lane            = threadIdx.x & 63;
    const int wave_in_block   = threadIdx.x >> 6;
    const int waves_per_block = blockDim.x >> 6;
    int       wave            = blockIdx.x * waves_per_block + wave_in_block;
    const int n_waves         = gridDim.x * waves_per_block;

    for (int e = wave; e < n_edges; e += n_waves) {
        const int s = src[e];   // wave-uniform -> broadcast from cache
        const int d = dst[e];

        const float4 a = *((const float4*)(h + (size_t)s * D_FEAT) + lane);
        const float4 b = *((const float4*)(h + (size_t)d * D_FEAT) + lane);

        float p = a.x * b.x + a.y * b.y;
        p += a.z * b.z;
        p += a.w * b.w;

        // 64-lane butterfly reduce
        #pragma unroll
        for (int off = 32; off > 0; off >>= 1)
            p += __shfl_down(p, off, 64);

        if (lane == 0) out[e] = p;
    }
}

extern "C" void kernel_launch(void* const* d_in, const int* in_sizes, int n_in,
                              void* d_out, int out_size, void* d_ws, size_t ws_size,
                              hipStream_t stream) {
    const float* h   = (const float*)d_in[0];
    const int*   src = (const int*)d_in[1];
    const int*   dst = (const int*)d_in[2];
    float*       out = (float*)d_out;

    const int n_edges = in_sizes[1];

    // 2048 blocks x 256 thr = 8192 waves = 32 waves/CU on 256 CUs (max resident)
    const int block = 256;
    const int waves_per_block = block / 64;
    int grid = (n_edges + waves_per_block - 1) / waves_per_block;
    if (grid > 2048) grid = 2048;

    edge_dot_kernel<<<grid, block, 0, stream>>>(h, src, dst, out, n_edges);
}

// Round 2
// 274.493 us; speedup vs baseline: 1.0309x; 1.0309x over previous
//
#include <hip/hip_runtime.h>

#define D_FEAT 256
#define UNROLL 4

// One wave (64 lanes) per edge; 4 edges per wave per iteration for MLP.
// Row of 256 f32 = 64 lanes x float4 (1024 B, perfectly coalesced).
__global__ __launch_bounds__(256) void edge_dot_kernel(
    const float* __restrict__ h,
    const int*   __restrict__ src,
    const int*   __restrict__ dst,
    float*       __restrict__ out,
    int n_edges)
{
    const int lane            = threadIdx.x & 63;
    const int wave_in_block   = threadIdx.x >> 6;
    const int waves_per_block = blockDim.x >> 6;
    const int wave            = blockIdx.x * waves_per_block + wave_in_block;
    const int n_waves         = gridDim.x * waves_per_block;

    const int stride = n_waves * UNROLL;

    for (int e0 = wave * UNROLL; e0 < n_edges; e0 += stride) {
        if (e0 + UNROLL <= n_edges) {
            // Wave-uniform 16B index loads -> scalar loads
            const int4 s4 = *(const int4*)(src + e0);
            const int4 d4 = *(const int4*)(dst + e0);

            // Issue all 8 row loads back-to-back (8 KB in flight per wave)
            const float4 a0 = *((const float4*)(h + (size_t)s4.x * D_FEAT) + lane);
            const float4 b0 = *((const float4*)(h + (size_t)d4.x * D_FEAT) + lane);
            const float4 a1 = *((const float4*)(h + (size_t)s4.y * D_FEAT) + lane);
            const float4 b1 = *((const float4*)(h + (size_t)d4.y * D_FEAT) + lane);
            const float4 a2 = *((const float4*)(h + (size_t)s4.z * D_FEAT) + lane);
            const float4 b2 = *((const float4*)(h + (size_t)d4.z * D_FEAT) + lane);
            const float4 a3 = *((const float4*)(h + (size_t)s4.w * D_FEAT) + lane);
            const float4 b3 = *((const float4*)(h + (size_t)d4.w * D_FEAT) + lane);

            float p0 = a0.x*b0.x + a0.y*b0.y + a0.z*b0.z + a0.w*b0.w;
            float p1 = a1.x*b1.x + a1.y*b1.y + a1.z*b1.z + a1.w*b1.w;
            float p2 = a2.x*b2.x + a2.y*b2.y + a2.z*b2.z + a2.w*b2.w;
            float p3 = a3.x*b3.x + a3.y*b3.y + a3.z*b3.z + a3.w*b3.w;

            // 4 independent butterfly reduces -> scheduler interleaves them
            #pragma unroll
            for (int off = 32; off > 0; off >>= 1) {
                p0 += __shfl_xor(p0, off, 64);
                p1 += __shfl_xor(p1, off, 64);
                p2 += __shfl_xor(p2, off, 64);
                p3 += __shfl_xor(p3, off, 64);
            }

            if (lane == 0) {
                out[e0 + 0] = p0;
                out[e0 + 1] = p1;
                out[e0 + 2] = p2;
                out[e0 + 3] = p3;
            }
        } else {
            // Tail: scalar path per remaining edge
            for (int e = e0; e < n_edges; ++e) {
                const int s = src[e];
                const int d = dst[e];
                const float4 a = *((const float4*)(h + (size_t)s * D_FEAT) + lane);
                const float4 b = *((const float4*)(h + (size_t)d * D_FEAT) + lane);
                float p = a.x*b.x + a.y*b.y + a.z*b.z + a.w*b.w;
                #pragma unroll
                for (int off = 32; off > 0; off >>= 1)
                    p += __shfl_xor(p, off, 64);
                if (lane == 0) out[e] = p;
            }
        }
    }
}

extern "C" void kernel_launch(void* const* d_in, const int* in_sizes, int n_in,
                              void* d_out, int out_size, void* d_ws, size_t ws_size,
                              hipStream_t stream) {
    const float* h   = (const float*)d_in[0];
    const int*   src = (const int*)d_in[1];
    const int*   dst = (const int*)d_in[2];
    float*       out = (float*)d_out;

    const int n_edges = in_sizes[1];

    // 2048 blocks x 256 thr = 8192 waves = 32 waves/CU on 256 CUs (max resident)
    const int block = 256;
    const int waves_per_block = block / 64;
    int grid = (n_edges + waves_per_block * UNROLL - 1) / (waves_per_block * UNROLL);
    if (grid > 2048) grid = 2048;

    edge_dot_kernel<<<grid, block, 0, stream>>>(h, src, dst, out, n_edges);
}

// Round 3
// 163.137 us; speedup vs baseline: 1.7346x; 1.6826x over previous
//
#include <hip/hip_runtime.h>
#include <hip/hip_fp16.h>

#define D_FEAT 256
#define UNROLL 4

// ---------- Kernel 1: compress h (fp32) -> fp16 in workspace ----------
__global__ __launch_bounds__(256) void convert_f32_to_f16(
    const float* __restrict__ h,
    unsigned int* __restrict__ hh,   // fp16 pairs packed as u32
    int n)                           // total f32 elements (multiple of 4)
{
    const int tid    = blockIdx.x * blockDim.x + threadIdx.x;
    const int stride = gridDim.x * blockDim.x;
    for (int j = tid * 4; j < n; j += stride * 4) {
        const float4 v = *(const float4*)(h + j);
        __half2 lo = __floats2half2_rn(v.x, v.y);
        __half2 hi = __floats2half2_rn(v.z, v.w);
        uint2 u;
        u.x = __builtin_bit_cast(unsigned int, lo);
        u.y = __builtin_bit_cast(unsigned int, hi);
        *(uint2*)(hh + (j >> 1)) = u;
    }
}

// ---------- Kernel 2: per-edge dot on fp16 rows, fp32 accumulate ----------
// Row = 256 f16 = 512 B = 64 lanes x uint2 (8 B/lane).
__global__ __launch_bounds__(256) void edge_dot_f16(
    const unsigned int* __restrict__ hh,
    const int* __restrict__ src,
    const int* __restrict__ dst,
    float*     __restrict__ out,
    int n_edges)
{
    const int lane            = threadIdx.x & 63;
    const int wave_in_block   = threadIdx.x >> 6;
    const int waves_per_block = blockDim.x >> 6;
    const int wave            = blockIdx.x * waves_per_block + wave_in_block;
    const int n_waves         = gridDim.x * waves_per_block;
    const int stride          = n_waves * UNROLL;

    // row base in u32 units: node * 128; lane covers u32[2*lane .. 2*lane+1]
    for (int e0 = wave * UNROLL; e0 < n_edges; e0 += stride) {
        if (e0 + UNROLL <= n_edges) {
            const int4 s4 = *(const int4*)(src + e0);
            const int4 d4 = *(const int4*)(dst + e0);

            const uint2 a0 = *((const uint2*)(hh + (size_t)s4.x * 128) + lane);
            const uint2 b0 = *((const uint2*)(hh + (size_t)d4.x * 128) + lane);
            const uint2 a1 = *((const uint2*)(hh + (size_t)s4.y * 128) + lane);
            const uint2 b1 = *((const uint2*)(hh + (size_t)d4.y * 128) + lane);
            const uint2 a2 = *((const uint2*)(hh + (size_t)s4.z * 128) + lane);
            const uint2 b2 = *((const uint2*)(hh + (size_t)d4.z * 128) + lane);
            const uint2 a3 = *((const uint2*)(hh + (size_t)s4.w * 128) + lane);
            const uint2 b3 = *((const uint2*)(hh + (size_t)d4.w * 128) + lane);

            float p0, p1, p2, p3;
            {
                float2 ax = __half22float2(__builtin_bit_cast(__half2, a0.x));
                float2 ay = __half22float2(__builtin_bit_cast(__half2, a0.y));
                float2 bx = __half22float2(__builtin_bit_cast(__half2, b0.x));
                float2 by = __half22float2(__builtin_bit_cast(__half2, b0.y));
                p0 = ax.x*bx.x + ax.y*bx.y + ay.x*by.x + ay.y*by.y;
            }
            {
                float2 ax = __half22float2(__builtin_bit_cast(__half2, a1.x));
                float2 ay = __half22float2(__builtin_bit_cast(__half2, a1.y));
                float2 bx = __half22float2(__builtin_bit_cast(__half2, b1.x));
                float2 by = __half22float2(__builtin_bit_cast(__half2, b1.y));
                p1 = ax.x*bx.x + ax.y*bx.y + ay.x*by.x + ay.y*by.y;
            }
            {
                float2 ax = __half22float2(__builtin_bit_cast(__half2, a2.x));
                float2 ay = __half22float2(__builtin_bit_cast(__half2, a2.y));
                float2 bx = __half22float2(__builtin_bit_cast(__half2, b2.x));
                float2 by = __half22float2(__builtin_bit_cast(__half2, b2.y));
                p2 = ax.x*bx.x + ax.y*bx.y + ay.x*by.x + ay.y*by.y;
            }
            {
                float2 ax = __half22float2(__builtin_bit_cast(__half2, a3.x));
                float2 ay = __half22float2(__builtin_bit_cast(__half2, a3.y));
                float2 bx = __half22float2(__builtin_bit_cast(__half2, b3.x));
                float2 by = __half22float2(__builtin_bit_cast(__half2, b3.y));
                p3 = ax.x*bx.x + ax.y*bx.y + ay.x*by.x + ay.y*by.y;
            }

            #pragma unroll
            for (int off = 32; off > 0; off >>= 1) {
                p0 += __shfl_xor(p0, off, 64);
                p1 += __shfl_xor(p1, off, 64);
                p2 += __shfl_xor(p2, off, 64);
                p3 += __shfl_xor(p3, off, 64);
            }

            if (lane == 0) {
                out[e0 + 0] = p0;
                out[e0 + 1] = p1;
                out[e0 + 2] = p2;
                out[e0 + 3] = p3;
            }
        } else {
            for (int e = e0; e < n_edges; ++e) {
                const int s = src[e];
                const int d = dst[e];
                const uint2 a = *((const uint2*)(hh + (size_t)s * 128) + lane);
                const uint2 b = *((const uint2*)(hh + (size_t)d * 128) + lane);
                float2 ax = __half22float2(__builtin_bit_cast(__half2, a.x));
                float2 ay = __half22float2(__builtin_bit_cast(__half2, a.y));
                float2 bx = __half22float2(__builtin_bit_cast(__half2, b.x));
                float2 by = __half22float2(__builtin_bit_cast(__half2, b.y));
                float p = ax.x*bx.x + ax.y*bx.y + ay.x*by.x + ay.y*by.y;
                #pragma unroll
                for (int off = 32; off > 0; off >>= 1)
                    p += __shfl_xor(p, off, 64);
                if (lane == 0) out[e] = p;
            }
        }
    }
}

// ---------- fp32 fallback (if workspace too small) ----------
__global__ __launch_bounds__(256) void edge_dot_f32(
    const float* __restrict__ h,
    const int*   __restrict__ src,
    const int*   __restrict__ dst,
    float*       __restrict__ out,
    int n_edges)
{
    const int lane            = threadIdx.x & 63;
    const int wave_in_block   = threadIdx.x >> 6;
    const int waves_per_block = blockDim.x >> 6;
    const int wave            = blockIdx.x * waves_per_block + wave_in_block;
    const int n_waves         = gridDim.x * waves_per_block;

    for (int e = wave; e < n_edges; e += n_waves) {
        const int s = src[e];
        const int d = dst[e];
        const float4 a = *((const float4*)(h + (size_t)s * D_FEAT) + lane);
        const float4 b = *((const float4*)(h + (size_t)d * D_FEAT) + lane);
        float p = a.x*b.x + a.y*b.y + a.z*b.z + a.w*b.w;
        #pragma unroll
        for (int off = 32; off > 0; off >>= 1)
            p += __shfl_xor(p, off, 64);
        if (lane == 0) out[e] = p;
    }
}

extern "C" void kernel_launch(void* const* d_in, const int* in_sizes, int n_in,
                              void* d_out, int out_size, void* d_ws, size_t ws_size,
                              hipStream_t stream) {
    const float* h   = (const float*)d_in[0];
    const int*   src = (const int*)d_in[1];
    const int*   dst = (const int*)d_in[2];
    float*       out = (float*)d_out;

    const int n_h     = in_sizes[0];   // 25.6M floats
    const int n_edges = in_sizes[1];

    const size_t need = (size_t)n_h * sizeof(unsigned short);

    const int block = 256;
    const int waves_per_block = block / 64;

    if (ws_size >= need) {
        unsigned int* hh = (unsigned int*)d_ws;

        int cgrid = (n_h / 4 + block - 1) / block;
        if (cgrid > 2048) cgrid = 2048;
        convert_f32_to_f16<<<cgrid, block, 0, stream>>>(h, hh, n_h);

        int grid = (n_edges + waves_per_block * UNROLL - 1) / (waves_per_block * UNROLL);
        if (grid > 2048) grid = 2048;
        edge_dot_f16<<<grid, block, 0, stream>>>(hh, src, dst, out, n_edges);
    } else {
        int grid = (n_edges + waves_per_block - 1) / waves_per_block;
        if (grid > 2048) grid = 2048;
        edge_dot_f32<<<grid, block, 0, stream>>>(h, src, dst, out, n_edges);
    }
}

// Round 4
// 88.975 us; speedup vs baseline: 3.1803x; 1.8335x over previous
//
#include <hip/hip_runtime.h>

#define D_FEAT 256
#define UNROLL 8

typedef float vfloat2 __attribute__((ext_vector_type(2)));

// ---------- Kernel 1: compress h (fp32) -> fp8 e4m3 (OCP) in workspace ----------
// 8 floats -> 8 fp8 bytes per thread per step.
__global__ __launch_bounds__(256) void convert_f32_to_fp8(
    const float* __restrict__ h,
    uint2* __restrict__ hh,          // 8 fp8 per uint2
    int n)                           // total f32 elements (multiple of 8)
{
    const int tid    = blockIdx.x * blockDim.x + threadIdx.x;
    const int stride = gridDim.x * blockDim.x;
    for (int j = tid * 8; j < n; j += stride * 8) {
        const float4 v0 = *(const float4*)(h + j);
        const float4 v1 = *(const float4*)(h + j + 4);
        unsigned int u0 = 0, u1 = 0;
        u0 = __builtin_amdgcn_cvt_pk_fp8_f32(v0.x, v0.y, u0, false);
        u0 = __builtin_amdgcn_cvt_pk_fp8_f32(v0.z, v0.w, u0, true);
        u1 = __builtin_amdgcn_cvt_pk_fp8_f32(v1.x, v1.y, u1, false);
        u1 = __builtin_amdgcn_cvt_pk_fp8_f32(v1.z, v1.w, u1, true);
        uint2 u; u.x = u0; u.y = u1;
        hh[j >> 3] = u;
    }
}

__device__ inline float dot_fp8(unsigned int a, unsigned int b) {
    vfloat2 al = __builtin_amdgcn_cvt_pk_f32_fp8(a, false);
    vfloat2 ah = __builtin_amdgcn_cvt_pk_f32_fp8(a, true);
    vfloat2 bl = __builtin_amdgcn_cvt_pk_f32_fp8(b, false);
    vfloat2 bh = __builtin_amdgcn_cvt_pk_f32_fp8(b, true);
    return al.x * bl.x + al.y * bl.y + ah.x * bh.x + ah.y * bh.y;
}

// merge two partial-sum sets: lanes with (lane&bit)==0 end up carrying a, else b
__device__ inline float merge2(float a, float b, int bit, int lane) {
    float keep = (lane & bit) ? b : a;
    float send = (lane & bit) ? a : b;
    return keep + __shfl_xor(send, bit, 64);
}

// ---------- Kernel 2: per-edge dot on fp8 rows, fp32 accumulate ----------
// Row = 256 fp8 = 256 B = 64 lanes x 4 B (one dword each).
__global__ __launch_bounds__(256) void edge_dot_fp8(
    const unsigned int* __restrict__ hh,
    const int* __restrict__ src,
    const int* __restrict__ dst,
    float*     __restrict__ out,
    int n_edges)
{
    const int lane            = threadIdx.x & 63;
    const int wave_in_block   = threadIdx.x >> 6;
    const int waves_per_block = blockDim.x >> 6;
    const int wave            = blockIdx.x * waves_per_block + wave_in_block;
    const int n_waves         = gridDim.x * waves_per_block;
    const int stride          = n_waves * UNROLL;

    for (int e0 = wave * UNROLL; e0 < n_edges; e0 += stride) {
        if (e0 + UNROLL <= n_edges) {
            const int4 sA = *(const int4*)(src + e0);
            const int4 sB = *(const int4*)(src + e0 + 4);
            const int4 dA = *(const int4*)(dst + e0);
            const int4 dB = *(const int4*)(dst + e0 + 4);

            // 16 independent dword gathers (256 B/wave each)
            const unsigned int a0 = hh[(size_t)sA.x * 64 + lane];
            const unsigned int b0 = hh[(size_t)dA.x * 64 + lane];
            const unsigned int a1 = hh[(size_t)sA.y * 64 + lane];
            const unsigned int b1 = hh[(size_t)dA.y * 64 + lane];
            const unsigned int a2 = hh[(size_t)sA.z * 64 + lane];
            const unsigned int b2 = hh[(size_t)dA.z * 64 + lane];
            const unsigned int a3 = hh[(size_t)sA.w * 64 + lane];
            const unsigned int b3 = hh[(size_t)dA.w * 64 + lane];
            const unsigned int a4 = hh[(size_t)sB.x * 64 + lane];
            const unsigned int b4 = hh[(size_t)dB.x * 64 + lane];
            const unsigned int a5 = hh[(size_t)sB.y * 64 + lane];
            const unsigned int b5 = hh[(size_t)dB.y * 64 + lane];
            const unsigned int a6 = hh[(size_t)sB.z * 64 + lane];
            const unsigned int b6 = hh[(size_t)dB.z * 64 + lane];
            const unsigned int a7 = hh[(size_t)sB.w * 64 + lane];
            const unsigned int b7 = hh[(size_t)dB.w * 64 + lane];

            float p0 = dot_fp8(a0, b0);
            float p1 = dot_fp8(a1, b1);
            float p2 = dot_fp8(a2, b2);
            float p3 = dot_fp8(a3, b3);
            float p4 = dot_fp8(a4, b4);
            float p5 = dot_fp8(a5, b5);
            float p6 = dot_fp8(a6, b6);
            float p7 = dot_fp8(a7, b7);

            // segmented butterfly: 10 shuffles reduce 8 values across 64 lanes;
            // lane l (l<8) ends holding the full sum of p_l
            float m01 = merge2(p0, p1, 1, lane);
            float m23 = merge2(p2, p3, 1, lane);
            float m45 = merge2(p4, p5, 1, lane);
            float m67 = merge2(p6, p7, 1, lane);
            float m03 = merge2(m01, m23, 2, lane);
            float m47 = merge2(m45, m67, 2, lane);
            float m   = merge2(m03, m47, 4, lane);
            m += __shfl_xor(m, 8, 64);
            m += __shfl_xor(m, 16, 64);
            m += __shfl_xor(m, 32, 64);

            if (lane < UNROLL) out[e0 + lane] = m;
        } else {
            for (int e = e0; e < n_edges; ++e) {
                const int s = src[e];
                const int d = dst[e];
                const unsigned int a = hh[(size_t)s * 64 + lane];
                const unsigned int b = hh[(size_t)d * 64 + lane];
                float p = dot_fp8(a, b);
                #pragma unroll
                for (int off = 32; off > 0; off >>= 1)
                    p += __shfl_xor(p, off, 64);
                if (lane == 0) out[e] = p;
            }
        }
    }
}

// ---------- fp32 fallback (if workspace too small) ----------
__global__ __launch_bounds__(256) void edge_dot_f32(
    const float* __restrict__ h,
    const int*   __restrict__ src,
    const int*   __restrict__ dst,
    float*       __restrict__ out,
    int n_edges)
{
    const int lane            = threadIdx.x & 63;
    const int wave_in_block   = threadIdx.x >> 6;
    const int waves_per_block = blockDim.x >> 6;
    const int wave            = blockIdx.x * waves_per_block + wave_in_block;
    const int n_waves         = gridDim.x * waves_per_block;

    for (int e = wave; e < n_edges; e += n_waves) {
        const int s = src[e];
        const int d = dst[e];
        const float4 a = *((const float4*)(h + (size_t)s * D_FEAT) + lane);
        const float4 b = *((const float4*)(h + (size_t)d * D_FEAT) + lane);
        float p = a.x*b.x + a.y*b.y + a.z*b.z + a.w*b.w;
        #pragma unroll
        for (int off = 32; off > 0; off >>= 1)
            p += __shfl_xor(p, off, 64);
        if (lane == 0) out[e] = p;
    }
}

extern "C" void kernel_launch(void* const* d_in, const int* in_sizes, int n_in,
                              void* d_out, int out_size, void* d_ws, size_t ws_size,
                              hipStream_t stream) {
    const float* h   = (const float*)d_in[0];
    const int*   src = (const int*)d_in[1];
    const int*   dst = (const int*)d_in[2];
    float*       out = (float*)d_out;

    const int n_h     = in_sizes[0];   // 25.6M floats
    const int n_edges = in_sizes[1];

    const size_t need = (size_t)n_h;   // 1 byte per element

    const int block = 256;
    const int waves_per_block = block / 64;

    if (ws_size >= need) {
        uint2* hh = (uint2*)d_ws;

        int cgrid = (n_h / 8 + block - 1) / block;
        if (cgrid > 2048) cgrid = 2048;
        convert_f32_to_fp8<<<cgrid, block, 0, stream>>>(h, hh, n_h);

        int grid = (n_edges + waves_per_block * UNROLL - 1) / (waves_per_block * UNROLL);
        if (grid > 2048) grid = 2048;
        edge_dot_fp8<<<grid, block, 0, stream>>>((const unsigned int*)hh, src, dst, out, n_edges);
    } else {
        int grid = (n_edges + waves_per_block - 1) / waves_per_block;
        if (grid > 2048) grid = 2048;
        edge_dot_f32<<<grid, block, 0, stream>>>(h, src, dst, out, n_edges);
    }
}